// Round 1
// 378.004 us; speedup vs baseline: 1.0056x; 1.0056x over previous
//
#include <hip/hip_runtime.h>
#include <stdint.h>

// EfficientSelfAttention on MI355X (gfx950). External I/O FP32; internals bf16
// MFMA. B=4, T=4096, D=1024, H=8, Dh=128. Scratch in __device__ globals.
// R6: XCD-aware swizzle for gemm_kv / gemm_qy (L2 locality for shared xn slab).
// R7: latency attack — gemm_kv/att/qy were stage->barrier->compute serialized
//     (MfmaUtil 21%, HBM 13%: pure stall). Now LDS double-buffered 2-phase:
//     issue global_load_lds for tile k+1 BEFORE computing tile k; single
//     barrier per K-step drains only residual latency (T3 minimal recipe).
//     Also: zrow fused into gemm_kv epilogue (atomicAdd per feature, sums the
//     same bf16-rounded terms), transpose+ln merged into prep_kernel (-2
//     dispatches). LDS budgets unchanged -> occupancy unchanged.

typedef unsigned short u16;
typedef __attribute__((ext_vector_type(8))) short bf16x8;
typedef __attribute__((ext_vector_type(4))) float f32x4;

// ------------------------------------------------------- device workspace
__device__ u16 g_WT[3][1024 * 1024];   // 6 MiB: WqT, WkT, WvT (bf16)
__device__ u16 g_xn[16777216];         // 32 MiB
__device__ u16 g_ekT[16777216];        // 32 MiB  [b][d][t]
__device__ u16 g_vvT[16777216];        // 32 MiB  [b][l][t]
__device__ float g_attp[8388608];      // 32 MiB  [kc*32+bh][d*128+l], 16 chunks
__device__ u16 g_attT[524288];         // 1 MiB   [bh][l*128+d]
__device__ float g_Z[4096];            //         [b*1024+d]

__device__ __forceinline__ float b2f(u16 u) {
  union { unsigned int i; float f; } c;
  c.i = ((unsigned int)u) << 16;
  return c.f;
}
__device__ __forceinline__ u16 f2b(float f) {
  union { float f; unsigned int i; } c;
  c.f = f;
  unsigned int r = c.i + 0x7fffu + ((c.i >> 16) & 1u);
  return (u16)(r >> 16);
}

__device__ __forceinline__ void gload16(const void* g, void* l) {
  __builtin_amdgcn_global_load_lds(
      reinterpret_cast<const __attribute__((address_space(1))) uint32_t*>(
          reinterpret_cast<uintptr_t>(g)),
      reinterpret_cast<__attribute__((address_space(3))) uint32_t*>(
          reinterpret_cast<uintptr_t>(l)),
      16, 0, 0);
}

// Stage 128x32 bf16 tile (row stride `stride` elems) into 8KB LDS [128][32].
__device__ __forceinline__ void stage128x32(const u16* g, int stride, char* lds,
                                            int wave, int lane) {
  const int r = wave * 32 + (lane >> 2);
  const int cb = (lane & 3) * 16;
  const char* gp = (const char*)g;
  gload16(gp + (size_t)r * stride * 2 + cb, lds + wave * 2048);
  gload16(gp + (size_t)(r + 16) * stride * 2 + cb, lds + wave * 2048 + 1024);
}

// A/B fragment from [128][32] LDS tile: row `row`, k = (lane>>4)*8 .. +7
__device__ __forceinline__ bf16x8 frag_ld(const char* lds, int row, int lane) {
  return *(const bf16x8*)(lds + row * 64 + ((lane >> 4) * 16));
}

// 16 MFMA on one staged 128x32 A/B tile pair.
__device__ __forceinline__ void tile_mfma(const char* As, const char* Bs,
                                          f32x4 (&acc)[4][4], int wm, int wn,
                                          int lane) {
  bf16x8 af[4], bfr[4];
#pragma unroll
  for (int i = 0; i < 4; i++) af[i] = frag_ld(As, wm * 64 + i * 16 + (lane & 15), lane);
#pragma unroll
  for (int j = 0; j < 4; j++) bfr[j] = frag_ld(Bs, wn * 64 + j * 16 + (lane & 15), lane);
#pragma unroll
  for (int i = 0; i < 4; i++)
#pragma unroll
    for (int j = 0; j < 4; j++)
      acc[i][j] = __builtin_amdgcn_mfma_f32_16x16x32_bf16(af[i], bfr[j], acc[i][j], 0, 0, 0);
}

// ---------------------------- prep: LN (blocks 0..16383) + W transpose (rest)
__global__ __launch_bounds__(256) void prep_kernel(const float* __restrict__ x,
                                                   const float* __restrict__ gamma,
                                                   const float* __restrict__ beta,
                                                   const float* __restrict__ wq,
                                                   const float* __restrict__ wk,
                                                   const float* __restrict__ wv) {
  __shared__ float ls[4], ls2[4];
  __shared__ u16 tile[32][33];
  const int bid = blockIdx.x;
  const int tid = threadIdx.x;
  if (bid < 16384) {
    if (bid < 16) g_Z[bid * 256 + tid] = 0.0f;  // per-launch Z reset
    const int wave = tid >> 6, lane = tid & 63;
    const float* xr = x + (size_t)bid * 1024;
    float4 u = ((const float4*)xr)[tid];
    float v0 = u.x, v1 = u.y, v2 = u.z, v3 = u.w;
    float s = v0 + v1 + v2 + v3;
    float s2 = v0 * v0 + v1 * v1 + v2 * v2 + v3 * v3;
#pragma unroll
    for (int off = 32; off > 0; off >>= 1) {
      s += __shfl_down(s, off);
      s2 += __shfl_down(s2, off);
    }
    if (lane == 0) { ls[wave] = s; ls2[wave] = s2; }
    __syncthreads();
    s = ls[0] + ls[1] + ls[2] + ls[3];
    s2 = ls2[0] + ls2[1] + ls2[2] + ls2[3];
    const float mu = s * (1.0f / 1024.0f);
    const float var = fmaxf(s2 * (1.0f / 1024.0f) - mu * mu, 0.0f);
    const float rstd = rsqrtf(var + 1e-5f);
    float4 g4 = ((const float4*)gamma)[tid];
    float4 be = ((const float4*)beta)[tid];
    ushort4 o;
    o.x = f2b((v0 - mu) * rstd * g4.x + be.x);
    o.y = f2b((v1 - mu) * rstd * g4.y + be.y);
    o.z = f2b((v2 - mu) * rstd * g4.z + be.z);
    o.w = f2b((v3 - mu) * rstd * g4.w + be.w);
    *(ushort4*)(g_xn + (size_t)bid * 1024 + tid * 4) = o;
  } else {
    const int id = bid - 16384;
    const int which = id >> 10;
    const int rem = id & 1023;
    const float* src = (which == 0) ? wq : (which == 1) ? wk : wv;
    u16* dst = g_WT[which];
    const int tx = tid & 31;
    const int ty = tid >> 5;
    const int c0 = (rem & 31) * 32, r0 = (rem >> 5) * 32;
#pragma unroll
    for (int i = 0; i < 4; i++)
      tile[ty + i * 8][tx] = f2b(src[(size_t)(r0 + ty + i * 8) * 1024 + c0 + tx]);
    __syncthreads();
#pragma unroll
    for (int i = 0; i < 4; i++)
      dst[(size_t)(c0 + ty + i * 8) * 1024 + r0 + tx] = tile[tx][ty + i * 8];
  }
}

// --------------------------------------------------------------- K/V GEMM
// z=0: ekT[b][d][t] = (m>0.5) ? exp(xn@Wk^T + bk) : 0   (+ Z row-sums, fused)
// z=1: vvT[b][l][t] = (xn@Wv^T + bv) * m
// 1-D grid 2048, XCD swizzle: c=L&7 owns m0 = c+8*(L>>7); (n0,z) = (L>>3)&15.
// LDS: 4x8KB double-buffered stage tiles, unioned with tT (34816B total).
__global__ __launch_bounds__(256) void gemm_kv(const float* __restrict__ bk,
                                               const float* __restrict__ bv,
                                               const float* __restrict__ mask) {
  __shared__ __align__(16) char smem[34816];
  char* A0 = smem;
  char* B0 = smem + 8192;
  char* A1 = smem + 16384;
  char* B1 = smem + 24576;
  u16* tT = (u16*)smem;  // [feature][token] 128x136, written AFTER K-loop
  const int tid = threadIdx.x, wave = tid >> 6, lane = tid & 63;
  const int L = blockIdx.x;
  const int c = L & 7;           // XCD (heuristic: round-robin dispatch)
  const int k = L >> 3;          // 0..255
  const int inner = k & 15;      // 16 blocks sharing one m0 slab
  const int n0 = (inner & 7) * 128;
  const int z = inner >> 3;
  const int m0 = (c + 8 * (k >> 4)) * 128;  // token block, m0%8 == XCD
  const u16* wt = z ? g_WT[2] : g_WT[1];
  const float* bias = z ? bv : bk;
  u16* outT = z ? g_vvT : g_ekT;
  const int b = m0 >> 12;
  const int t0 = m0 & 4095;
  const int wm = wave & 1, wn = wave >> 1;
  const u16* Ag = g_xn + (size_t)m0 * 1024;
  const u16* Bg = wt + (size_t)n0 * 1024;

  f32x4 zero = {0.f, 0.f, 0.f, 0.f};
  f32x4 acc[4][4];
#pragma unroll
  for (int i = 0; i < 4; i++)
#pragma unroll
    for (int j = 0; j < 4; j++) acc[i][j] = zero;

  // 2-phase pipeline: prefetch k+1 issued before compute k; 1 barrier/K-step.
  stage128x32(Ag, 1024, A0, wave, lane);
  stage128x32(Bg, 1024, B0, wave, lane);
  __syncthreads();
  for (int k0 = 0; k0 < 1024; k0 += 64) {
    stage128x32(Ag + k0 + 32, 1024, A1, wave, lane);
    stage128x32(Bg + k0 + 32, 1024, B1, wave, lane);
    tile_mfma(A0, B0, acc, wm, wn, lane);
    __syncthreads();  // drains A1/B1 loads + A0/B0 reads
    if (k0 + 64 < 1024) {
      stage128x32(Ag + k0 + 64, 1024, A0, wave, lane);
      stage128x32(Bg + k0 + 64, 1024, B0, wave, lane);
    }
    tile_mfma(A1, B1, acc, wm, wn, lane);
    __syncthreads();  // drains A0/B0 loads + A1/B1 reads; final iter: frees smem for tT
  }

  float fsum[4] = {0.f, 0.f, 0.f, 0.f};
#pragma unroll
  for (int i = 0; i < 4; i++)
#pragma unroll
    for (int r = 0; r < 4; r++) {
      const int rowl = wm * 64 + i * 16 + (lane >> 4) * 4 + r;  // local token
      const float mv = mask[m0 + rowl];
#pragma unroll
      for (int j = 0; j < 4; j++) {
        const int coll = wn * 64 + j * 16 + (lane & 15);  // local feature
        const float a = acc[i][j][r] + bias[n0 + coll];
        float o;
        if (z)
          o = a * mv;
        else
          o = (mv > 0.5f) ? __expf(fminf(a, 30.0f)) : 0.0f;
        const u16 ob = f2b(o);
        tT[coll * 136 + rowl] = ob;
        if (!z) fsum[j] += b2f(ob);  // sum rounded values == old zrow semantics
      }
    }
  if (!z) {
    // fused zrow: reduce over the 4 token-subgroups (lane>>4) then one
    // device-scope atomicAdd per feature per wave (wm=0/1 halves both add).
#pragma unroll
    for (int j = 0; j < 4; j++) {
      float s = fsum[j];
      s += __shfl_xor(s, 16);
      s += __shfl_xor(s, 32);
      if (lane < 16) atomicAdd(&g_Z[b * 1024 + n0 + wn * 64 + j * 16 + lane], s);
    }
  }
  __syncthreads();
  const size_t gbase = (size_t)b * (1024 * 4096) + (size_t)n0 * 4096 + t0;
#pragma unroll
  for (int u = 0; u < 8; u++) {
    const int v = u * 256 + tid;
    const int cc = v >> 4, rb = (v & 15) * 8;
    uint4 val = *(const uint4*)&tT[cc * 136 + rb];
    *(uint4*)(outT + gbase + (size_t)cc * 4096 + rb) = val;
  }
}

// ------------------------------------------------------------- att GEMM
// attp[kc][bh][d][l] = sum_{t in 256-chunk kc} ekT[b][h*128+d][t]*vvT[b][h*128+l][t]
__global__ __launch_bounds__(256) void gemm_att() {
  __shared__ __align__(16) char smem[32768];
  char* A0 = smem;
  char* B0 = smem + 8192;
  char* A1 = smem + 16384;
  char* B1 = smem + 24576;
  const int tid = threadIdx.x, wave = tid >> 6, lane = tid & 63;
  const int kc = blockIdx.x;  // 0..15
  const int bh = blockIdx.y;  // 0..31
  const int b = bh >> 3, h = bh & 7;
  const size_t base = (size_t)b * (1024 * 4096) + (size_t)(h * 128) * 4096;
  const int wm = wave & 1, wn = wave >> 1;
  const u16* Ag = g_ekT + base + kc * 256;
  const u16* Bg = g_vvT + base + kc * 256;

  f32x4 zero = {0.f, 0.f, 0.f, 0.f};
  f32x4 acc[4][4];
#pragma unroll
  for (int i = 0; i < 4; i++)
#pragma unroll
    for (int j = 0; j < 4; j++) acc[i][j] = zero;

  stage128x32(Ag, 4096, A0, wave, lane);
  stage128x32(Bg, 4096, B0, wave, lane);
  __syncthreads();
  for (int kt = 0; kt < 256; kt += 64) {
    stage128x32(Ag + kt + 32, 4096, A1, wave, lane);
    stage128x32(Bg + kt + 32, 4096, B1, wave, lane);
    tile_mfma(A0, B0, acc, wm, wn, lane);
    __syncthreads();
    if (kt + 64 < 256) {
      stage128x32(Ag + kt + 64, 4096, A0, wave, lane);
      stage128x32(Bg + kt + 64, 4096, B0, wave, lane);
    }
    tile_mfma(A1, B1, acc, wm, wn, lane);
    __syncthreads();
  }

  float* op = g_attp + ((size_t)(kc * 32 + bh)) * 16384;
#pragma unroll
  for (int i = 0; i < 4; i++)
#pragma unroll
    for (int r = 0; r < 4; r++) {
      const int row = wm * 64 + i * 16 + (lane >> 4) * 4 + r;
#pragma unroll
      for (int j = 0; j < 4; j++) {
        const int col = wn * 64 + j * 16 + (lane & 15);
        op[row * 128 + col] = acc[i][j][r];
      }
    }
}

// ------------------------------------- reduce partials, /Z, store attT[bh][l][d]
__global__ __launch_bounds__(256) void attnorm_kernel() {
  const int bh = blockIdx.x;
  const int b = bh >> 3, h = bh & 7;
  const int tid = threadIdx.x;
  __shared__ float Zl[128];
  if (tid < 128) Zl[tid] = fmaxf(g_Z[b * 1024 + h * 128 + tid], 1e-30f);
  __syncthreads();
  const int i0 = blockIdx.y * 2048;
  for (int i = i0 + tid; i < i0 + 2048; i += 256) {
    const int d = i >> 7, l = i & 127;
    float s = 0.f;
#pragma unroll
    for (int c = 0; c < 16; c++) s += g_attp[((size_t)(c * 32 + bh)) * 16384 + i];
    g_attT[(size_t)bh * 16384 + l * 128 + d] = f2b(s / Zl[d]);
  }
}

// ---------------------------------------------------------- fused q + y
// 1-D grid 1024, XCD swizzle: c=L&7, k=L>>3; m0 = c+8*(k>>3); h = k&7.
// LDS: phase-1 dbuf (32KB) unioned under qs (34816B); phase-2 B dbuf in the
// 16KB above it. Total 51200+zqp == old 52224 -> occupancy unchanged.
__global__ __launch_bounds__(256) void gemm_qy(const float* __restrict__ bq,
                                               const float* __restrict__ x,
                                               float* __restrict__ out) {
  __shared__ __align__(16) char smem[51200];
  __shared__ float zqp[2][128];
  char* A0 = smem;
  char* B0 = smem + 8192;
  char* A1 = smem + 16384;
  char* B1 = smem + 24576;
  u16* qs = (u16*)smem;            // [token][feature] 128x136 padded (34816B)
  char* C0 = smem + 34816;         // phase-2 attT tile dbuf
  char* C1 = smem + 43008;
  const int tid = threadIdx.x, wave = tid >> 6, lane = tid & 63;
  const int L = blockIdx.x;
  const int c = L & 7;
  const int k = L >> 3;              // 0..127
  const int h = k & 7;               // head
  const int m0 = (c + 8 * (k >> 3)) * 128;  // token block, m0%8 == XCD
  const int b = m0 >> 12;
  const int bh = b * 8 + h;
  const int wm = wave & 1, wn = wave >> 1;
  const u16* Ag = g_xn + (size_t)m0 * 1024;
  const u16* Bg = g_WT[0] + (size_t)(h * 128) * 1024;
  const u16* Cg = g_attT + (size_t)bh * 16384;

  f32x4 zero = {0.f, 0.f, 0.f, 0.f};
  f32x4 acc[4][4];
#pragma unroll
  for (int i = 0; i < 4; i++)
#pragma unroll
    for (int j = 0; j < 4; j++) acc[i][j] = zero;

  // phase 1: q = xn @ WqT[head rows], 2-phase pipelined
  stage128x32(Ag, 1024, A0, wave, lane);
  stage128x32(Bg, 1024, B0, wave, lane);
  __syncthreads();
  for (int k0 = 0; k0 < 1024; k0 += 64) {
    stage128x32(Ag + k0 + 32, 1024, A1, wave, lane);
    stage128x32(Bg + k0 + 32, 1024, B1, wave, lane);
    tile_mfma(A0, B0, acc, wm, wn, lane);
    __syncthreads();
    if (k0 + 64 < 1024) {
      stage128x32(Ag + k0 + 64, 1024, A0, wave, lane);
      stage128x32(Bg + k0 + 64, 1024, B0, wave, lane);
    }
    tile_mfma(A1, B1, acc, wm, wn, lane);
    __syncthreads();
  }

  // prefetch phase-2 B tile 0 now; latency hides under epilogue-1 VALU work
  stage128x32(Cg, 128, C0, wave, lane);

  // epilogue 1: exp (clamped), store to qs (overlaps drained A/B bufs), row-sums
#pragma unroll
  for (int i = 0; i < 4; i++)
#pragma unroll
    for (int r = 0; r < 4; r++) {
      const int rowl = wm * 64 + i * 16 + (lane >> 4) * 4 + r;
      float rs = 0.f;
#pragma unroll
      for (int j = 0; j < 4; j++) {
        const int coll = wn * 64 + j * 16 + (lane & 15);
        const float e = __expf(fminf(acc[i][j][r] + bq[h * 128 + coll], 30.0f));
        qs[rowl * 136 + coll] = f2b(e);
        rs += e;
      }
      rs += __shfl_xor(rs, 1);
      rs += __shfl_xor(rs, 2);
      rs += __shfl_xor(rs, 4);
      rs += __shfl_xor(rs, 8);
      if ((lane & 15) == 0) zqp[wn][rowl] = rs;
    }
  __syncthreads();  // qs visible; C0 prefetch drained

  // phase 2: y = qs @ attT[bh]^T  (K = 128), B double-buffered
  f32x4 acc2[4][4];
#pragma unroll
  for (int i = 0; i < 4; i++)
#pragma unroll
    for (int j = 0; j < 4; j++) acc2[i][j] = zero;

  for (int k0 = 0; k0 < 128; k0 += 64) {
    stage128x32(Cg + k0 + 32, 128, C1, wave, lane);
    {
      bf16x8 af[4], bfr[4];
#pragma unroll
      for (int i = 0; i < 4; i++)
        af[i] = *(const bf16x8*)&qs[(wm * 64 + i * 16 + (lane & 15)) * 136 + k0 + (lane >> 4) * 8];
#pragma unroll
      for (int j = 0; j < 4; j++) bfr[j] = frag_ld(C0, wn * 64 + j * 16 + (lane & 15), lane);
#pragma unroll
      for (int i = 0; i < 4; i++)
#pragma unroll
        for (int j = 0; j < 4; j++)
          acc2[i][j] = __builtin_amdgcn_mfma_f32_16x16x32_bf16(af[i], bfr[j], acc2[i][j], 0, 0, 0);
    }
    __syncthreads();
    if (k0 + 64 < 128) stage128x32(Cg + k0 + 64, 128, C0, wave, lane);
    {
      bf16x8 af[4], bfr[4];
#pragma unroll
      for (int i = 0; i < 4; i++)
        af[i] = *(const bf16x8*)&qs[(wm * 64 + i * 16 + (lane & 15)) * 136 + k0 + 32 + (lane >> 4) * 8];
#pragma unroll
      for (int j = 0; j < 4; j++) bfr[j] = frag_ld(C1, wn * 64 + j * 16 + (lane & 15), lane);
#pragma unroll
      for (int i = 0; i < 4; i++)
#pragma unroll
        for (int j = 0; j < 4; j++)
          acc2[i][j] = __builtin_amdgcn_mfma_f32_16x16x32_bf16(af[i], bfr[j], acc2[i][j], 0, 0, 0);
    }
    __syncthreads();
  }

  // epilogue 2: out = x + y / Zq  (fp32)
#pragma unroll
  for (int i = 0; i < 4; i++)
#pragma unroll
    for (int r = 0; r < 4; r++) {
      const int rowl = wm * 64 + i * 16 + (lane >> 4) * 4 + r;
      const float zq = fmaxf(zqp[0][rowl] + zqp[1][rowl], 1e-30f);
      const size_t n = (size_t)m0 + rowl;
#pragma unroll
      for (int j = 0; j < 4; j++) {
        const int coll = wn * 64 + j * 16 + (lane & 15);
        const size_t idx = n * 1024 + h * 128 + coll;
        out[idx] = x[idx] + acc2[i][j][r] / zq;
      }
    }
}

// ----------------------------------------------------------------- launch
extern "C" void kernel_launch(void* const* d_in, const int* in_sizes, int n_in,
                              void* d_out, int out_size, void* d_ws, size_t ws_size,
                              hipStream_t stream) {
  const float* x = (const float*)d_in[0];
  const float* mask = (const float*)d_in[1];
  const float* Wq = (const float*)d_in[2];
  const float* bq = (const float*)d_in[3];
  const float* Wk = (const float*)d_in[4];
  const float* bk = (const float*)d_in[5];
  const float* Wv = (const float*)d_in[6];
  const float* bv = (const float*)d_in[7];
  const float* gamma = (const float*)d_in[8];
  const float* beta = (const float*)d_in[9];
  float* out = (float*)d_out;
  (void)d_ws; (void)ws_size;

  prep_kernel<<<dim3(16384 + 3072), 256, 0, stream>>>(x, gamma, beta, Wq, Wk, Wv);
  gemm_kv<<<dim3(2048), 256, 0, stream>>>(bk, bv, mask);
  gemm_att<<<dim3(16, 32), 256, 0, stream>>>();
  attnorm_kernel<<<dim3(32, 8), 256, 0, stream>>>();
  gemm_qy<<<dim3(1024), 256, 0, stream>>>(bq, x, out);
}

// Round 2
// 335.361 us; speedup vs baseline: 1.1335x; 1.1272x over previous
//
#include <hip/hip_runtime.h>
#include <stdint.h>

// EfficientSelfAttention on MI355X (gfx950). External I/O FP32; internals bf16
// MFMA. B=4, T=4096, D=1024, H=8, Dh=128. Scratch in __device__ globals.
// R8: gemm_kv ported to the 256^2 8-phase counted-vmcnt template (T3+T4+T2+T5):
//     512 thr / 8 waves (2Mx4N), BK=64, 128KiB LDS dbuf, raw s_barrier (no
//     vmcnt(0) drain in loop), chunk-XOR LDS swizzle applied on BOTH sides
//     (pre-swizzled global source for global_load_lds + swizzled ds_read).
//     Waits are counted: vmcnt(4)/vmcnt(2) drain only loads issued >=2 phases
//     earlier; schedule verified phase-by-phase (see comments in kernel).
//     Epilogue reuses LDS for 256x256 transpose; fused zrow atomics kept.

typedef unsigned short u16;
typedef __attribute__((ext_vector_type(8))) short bf16x8;
typedef __attribute__((ext_vector_type(4))) float f32x4;

// ------------------------------------------------------- device workspace
__device__ u16 g_WT[3][1024 * 1024];   // 6 MiB: WqT, WkT, WvT (bf16)
__device__ u16 g_xn[16777216];         // 32 MiB
__device__ u16 g_ekT[16777216];        // 32 MiB  [b][d][t]
__device__ u16 g_vvT[16777216];        // 32 MiB  [b][l][t]
__device__ float g_attp[8388608];      // 32 MiB  [kc*32+bh][d*128+l], 16 chunks
__device__ u16 g_attT[524288];         // 1 MiB   [bh][l*128+d]
__device__ float g_Z[4096];            //         [b*1024+d]

__device__ __forceinline__ float b2f(u16 u) {
  union { unsigned int i; float f; } c;
  c.i = ((unsigned int)u) << 16;
  return c.f;
}
__device__ __forceinline__ u16 f2b(float f) {
  union { float f; unsigned int i; } c;
  c.f = f;
  unsigned int r = c.i + 0x7fffu + ((c.i >> 16) & 1u);
  return (u16)(r >> 16);
}

__device__ __forceinline__ void gload16(const void* g, void* l) {
  __builtin_amdgcn_global_load_lds(
      reinterpret_cast<const __attribute__((address_space(1))) uint32_t*>(
          reinterpret_cast<uintptr_t>(g)),
      reinterpret_cast<__attribute__((address_space(3))) uint32_t*>(
          reinterpret_cast<uintptr_t>(l)),
      16, 0, 0);
}

// Stage 128x32 bf16 tile (row stride `stride` elems) into 8KB LDS [128][32].
// (used by gemm_att / gemm_qy — unchanged)
__device__ __forceinline__ void stage128x32(const u16* g, int stride, char* lds,
                                            int wave, int lane) {
  const int r = wave * 32 + (lane >> 2);
  const int cb = (lane & 3) * 16;
  const char* gp = (const char*)g;
  gload16(gp + (size_t)r * stride * 2 + cb, lds + wave * 2048);
  gload16(gp + (size_t)(r + 16) * stride * 2 + cb, lds + wave * 2048 + 1024);
}

// A/B fragment from [128][32] LDS tile: row `row`, k = (lane>>4)*8 .. +7
__device__ __forceinline__ bf16x8 frag_ld(const char* lds, int row, int lane) {
  return *(const bf16x8*)(lds + row * 64 + ((lane >> 4) * 16));
}

// 16 MFMA on one staged 128x32 A/B tile pair (gemm_att / gemm_qy).
__device__ __forceinline__ void tile_mfma(const char* As, const char* Bs,
                                          f32x4 (&acc)[4][4], int wm, int wn,
                                          int lane) {
  bf16x8 af[4], bfr[4];
#pragma unroll
  for (int i = 0; i < 4; i++) af[i] = frag_ld(As, wm * 64 + i * 16 + (lane & 15), lane);
#pragma unroll
  for (int j = 0; j < 4; j++) bfr[j] = frag_ld(Bs, wn * 64 + j * 16 + (lane & 15), lane);
#pragma unroll
  for (int i = 0; i < 4; i++)
#pragma unroll
    for (int j = 0; j < 4; j++)
      acc[i][j] = __builtin_amdgcn_mfma_f32_16x16x32_bf16(af[i], bfr[j], acc[i][j], 0, 0, 0);
}

// ---------------- 256^2 8-phase helpers (gemm_kv) ----------------
// [256][64]-bf16 LDS tile, 128B rows. Chunk-XOR swizzle: 16B-chunk slot s of
// row r holds global chunk (s ^ (r&7)). Stage: linear LDS dest (required by
// global_load_lds) + inverse-swizzled per-lane GLOBAL source. Read: swizzled
// ds_read address. Same involution on both sides (rule #21).
// Half-tiles defined by the READ pattern:
//   A-ht(h) = rows {r: (r>>6)&1 == h}  (quad rh reads rows wm*128+rh*64..+63)
//   B-ht(h) = rows {r: (r>>5)&1 == h}  (quad ch reads rows wn*64+ch*32..+31)
__device__ __forceinline__ void stageA256(char* buf, const u16* gsrc, int h,
                                          int wave, int lane) {
#pragma unroll
  for (int i = 0; i < 2; i++) {
    const int ib = i * 64 + wave * 8;  // idx base (wave-uniform)
    const int rowb = (ib & 63) | ((ib & 64) << 1) | (h << 6);
    const int row = rowb + (lane >> 3);
    const int cc = (lane & 7) ^ (row & 7);  // inverse-swizzled source chunk
    gload16((const char*)gsrc + ((size_t)row * 1024 + cc * 8) * 2,
            buf + rowb * 128);
  }
}
__device__ __forceinline__ void stageB256(char* buf, const u16* gsrc, int h,
                                          int wave, int lane) {
#pragma unroll
  for (int i = 0; i < 2; i++) {
    const int ib = i * 64 + wave * 8;
    const int rowb = (ib & 31) | ((ib & 96) << 1) | (h << 5);
    const int row = rowb + (lane >> 3);
    const int cc = (lane & 7) ^ (row & 7);
    gload16((const char*)gsrc + ((size_t)row * 1024 + cc * 8) * 2,
            buf + rowb * 128);
  }
}
// frag read: row R (includes lane&15), k-step ks: global chunk = ks*4 + q
__device__ __forceinline__ bf16x8 fragS(const char* buf, int R, int ks, int lane) {
  const int q = lane >> 4;
  return *(const bf16x8*)(buf + R * 128 + ((((ks << 2) + q) ^ (R & 7)) << 4));
}

// ---------------------------- prep: LN (blocks 0..16383) + W transpose (rest)
__global__ __launch_bounds__(256) void prep_kernel(const float* __restrict__ x,
                                                   const float* __restrict__ gamma,
                                                   const float* __restrict__ beta,
                                                   const float* __restrict__ wq,
                                                   const float* __restrict__ wk,
                                                   const float* __restrict__ wv) {
  __shared__ float ls[4], ls2[4];
  __shared__ u16 tile[32][33];
  const int bid = blockIdx.x;
  const int tid = threadIdx.x;
  if (bid < 16384) {
    if (bid < 16) g_Z[bid * 256 + tid] = 0.0f;  // per-launch Z reset
    const int wave = tid >> 6, lane = tid & 63;
    const float* xr = x + (size_t)bid * 1024;
    float4 u = ((const float4*)xr)[tid];
    float v0 = u.x, v1 = u.y, v2 = u.z, v3 = u.w;
    float s = v0 + v1 + v2 + v3;
    float s2 = v0 * v0 + v1 * v1 + v2 * v2 + v3 * v3;
#pragma unroll
    for (int off = 32; off > 0; off >>= 1) {
      s += __shfl_down(s, off);
      s2 += __shfl_down(s2, off);
    }
    if (lane == 0) { ls[wave] = s; ls2[wave] = s2; }
    __syncthreads();
    s = ls[0] + ls[1] + ls[2] + ls[3];
    s2 = ls2[0] + ls2[1] + ls2[2] + ls2[3];
    const float mu = s * (1.0f / 1024.0f);
    const float var = fmaxf(s2 * (1.0f / 1024.0f) - mu * mu, 0.0f);
    const float rstd = rsqrtf(var + 1e-5f);
    float4 g4 = ((const float4*)gamma)[tid];
    float4 be = ((const float4*)beta)[tid];
    ushort4 o;
    o.x = f2b((v0 - mu) * rstd * g4.x + be.x);
    o.y = f2b((v1 - mu) * rstd * g4.y + be.y);
    o.z = f2b((v2 - mu) * rstd * g4.z + be.z);
    o.w = f2b((v3 - mu) * rstd * g4.w + be.w);
    *(ushort4*)(g_xn + (size_t)bid * 1024 + tid * 4) = o;
  } else {
    const int id = bid - 16384;
    const int which = id >> 10;
    const int rem = id & 1023;
    const float* src = (which == 0) ? wq : (which == 1) ? wk : wv;
    u16* dst = g_WT[which];
    const int tx = tid & 31;
    const int ty = tid >> 5;
    const int c0 = (rem & 31) * 32, r0 = (rem >> 5) * 32;
#pragma unroll
    for (int i = 0; i < 4; i++)
      tile[ty + i * 8][tx] = f2b(src[(size_t)(r0 + ty + i * 8) * 1024 + c0 + tx]);
    __syncthreads();
#pragma unroll
    for (int i = 0; i < 4; i++)
      dst[(size_t)(c0 + ty + i * 8) * 1024 + r0 + tx] = tile[tx][ty + i * 8];
  }
}

// --------------------------------------------------------------- K/V GEMM
// 256^2 tile, 8-phase counted-vmcnt schedule. Grid 512 = 64 m-tiles x 8
// n-variants (4 n0 per z x 2 z). XCD swizzle: c=L&7 -> m-tile = c + 8*(L>>6);
// the 8 n-variants of one m-tile are consecutive L on one XCD (share A-slab).
// z=0: ekT[b][d][t] = (m>0.5) ? exp(xn@Wk^T + bk) : 0   (+ fused Z row-sums)
// z=1: vvT[b][l][t] = (xn@Wv^T + bv) * m
//
// Schedule per K-tile t (buffer p=t&1; staging tile t+1 into buffer p^1):
//  ph1 quad(0,0): ds A-ht0(12 rd w/ B) ; stage A-ht0+B-ht0 (4 ld); vmcnt(4)
//  ph2 quad(0,1): ds B-ht1 (4 rd)      ; stage B-ht1 (2 ld)      ; no wait
//  ph3 quad(1,1): ds A-ht1 (8 rd)      ; stage A-ht1 (2 ld)      ; vmcnt(4)
//  ph4 quad(1,0): regs only            ; no stage                ; vmcnt(2)
// Each vmcnt drains only loads issued >=2 phases earlier; a drained load's
// consumers read after the NEXT mid-phase barrier => cross-wave safe.
// Last tile (t=15): no staging; ph1 uses vmcnt(0) to cover its A-ht1 reads.
__global__ __launch_bounds__(512, 2) void gemm_kv(const float* __restrict__ bk,
                                                  const float* __restrict__ bv,
                                                  const float* __restrict__ mask) {
  __shared__ __align__(16) char smem[131072];
  const int tid = threadIdx.x, wave = tid >> 6, lane = tid & 63;
  const int L = blockIdx.x;
  const int mt = (L & 7) + 8 * (L >> 6);
  const int nt = (L >> 3) & 7;
  const int n0 = (nt & 3) * 256;
  const int z = nt >> 2;
  const int m0 = mt * 256;
  const u16* wt = z ? g_WT[2] : g_WT[1];
  const float* bias = z ? bv : bk;
  u16* outT = z ? g_vvT : g_ekT;
  const int b = m0 >> 12;
  const int t0 = m0 & 4095;
  const int wm = wave >> 2, wn = wave & 3;
  const u16* Ag = g_xn + (size_t)m0 * 1024;
  const u16* Bg = wt + (size_t)n0 * 1024;

  f32x4 zero = {0.f, 0.f, 0.f, 0.f};
  f32x4 acc[8][4];
#pragma unroll
  for (int i = 0; i < 8; i++)
#pragma unroll
    for (int j = 0; j < 4; j++) acc[i][j] = zero;
  bf16x8 a[4][2], bB[2][2][2];

  // prologue: stage tile 0 fully into buffer 0, full drain (allowed once)
  stageA256(smem, Ag, 0, wave, lane);
  stageB256(smem + 65536, Bg, 0, wave, lane);
  stageA256(smem, Ag, 1, wave, lane);
  stageB256(smem + 65536, Bg, 1, wave, lane);
  asm volatile("s_waitcnt vmcnt(0)" ::: "memory");
  __builtin_amdgcn_s_barrier();

#pragma unroll 1
  for (int t = 0; t < 16; ++t) {
    const int p = t & 1;
    char* Ab = smem + p * 32768;
    char* Bb = smem + 65536 + p * 32768;
    char* An = smem + (p ^ 1) * 32768;
    char* Bn = smem + 65536 + (p ^ 1) * 32768;
    const u16* Agn = Ag + (t + 1) * 64;
    const u16* Bgn = Bg + (t + 1) * 64;
    const bool st = t < 15;

    // ---- phase 1: quad(0,0) ----
#pragma unroll
    for (int rf = 0; rf < 4; rf++) {
      const int R = wm * 128 + rf * 16 + (lane & 15);
#pragma unroll
      for (int ks = 0; ks < 2; ks++) a[rf][ks] = fragS(Ab, R, ks, lane);
    }
#pragma unroll
    for (int cf = 0; cf < 2; cf++) {
      const int R = wn * 64 + cf * 16 + (lane & 15);
#pragma unroll
      for (int ks = 0; ks < 2; ks++) bB[0][cf][ks] = fragS(Bb, R, ks, lane);
    }
    if (st) {
      stageA256(An, Agn, 0, wave, lane);
      stageB256(Bn, Bgn, 0, wave, lane);
      asm volatile("s_waitcnt vmcnt(4)" ::: "memory");
    } else {
      asm volatile("s_waitcnt vmcnt(0)" ::: "memory");
    }
    __builtin_amdgcn_s_barrier();
    asm volatile("s_waitcnt lgkmcnt(0)" ::: "memory");
    __builtin_amdgcn_sched_barrier(0);
    __builtin_amdgcn_s_setprio(1);
#pragma unroll
    for (int rf = 0; rf < 4; rf++)
#pragma unroll
      for (int cf = 0; cf < 2; cf++)
#pragma unroll
        for (int ks = 0; ks < 2; ks++)
          acc[rf][cf] = __builtin_amdgcn_mfma_f32_16x16x32_bf16(
              a[rf][ks], bB[0][cf][ks], acc[rf][cf], 0, 0, 0);
    __builtin_amdgcn_s_setprio(0);
    __builtin_amdgcn_s_barrier();
    __builtin_amdgcn_sched_barrier(0);

    // ---- phase 2: quad(0,1) ----
#pragma unroll
    for (int cf = 0; cf < 2; cf++) {
      const int R = wn * 64 + 32 + cf * 16 + (lane & 15);
#pragma unroll
      for (int ks = 0; ks < 2; ks++) bB[1][cf][ks] = fragS(Bb, R, ks, lane);
    }
    if (st) stageB256(Bn, Bgn, 1, wave, lane);
    __builtin_amdgcn_s_barrier();
    asm volatile("s_waitcnt lgkmcnt(0)" ::: "memory");
    __builtin_amdgcn_sched_barrier(0);
    __builtin_amdgcn_s_setprio(1);
#pragma unroll
    for (int rf = 0; rf < 4; rf++)
#pragma unroll
      for (int cf = 0; cf < 2; cf++)
#pragma unroll
        for (int ks = 0; ks < 2; ks++)
          acc[rf][2 + cf] = __builtin_amdgcn_mfma_f32_16x16x32_bf16(
              a[rf][ks], bB[1][cf][ks], acc[rf][2 + cf], 0, 0, 0);
    __builtin_amdgcn_s_setprio(0);
    __builtin_amdgcn_s_barrier();
    __builtin_amdgcn_sched_barrier(0);

    // ---- phase 3: quad(1,1) ----
#pragma unroll
    for (int rf = 0; rf < 4; rf++) {
      const int R = wm * 128 + 64 + rf * 16 + (lane & 15);
#pragma unroll
      for (int ks = 0; ks < 2; ks++) a[rf][ks] = fragS(Ab, R, ks, lane);
    }
    if (st) stageA256(An, Agn, 1, wave, lane);
    asm volatile("s_waitcnt vmcnt(4)" ::: "memory");
    __builtin_amdgcn_s_barrier();
    asm volatile("s_waitcnt lgkmcnt(0)" ::: "memory");
    __builtin_amdgcn_sched_barrier(0);
    __builtin_amdgcn_s_setprio(1);
#pragma unroll
    for (int rf = 0; rf < 4; rf++)
#pragma unroll
      for (int cf = 0; cf < 2; cf++)
#pragma unroll
        for (int ks = 0; ks < 2; ks++)
          acc[4 + rf][2 + cf] = __builtin_amdgcn_mfma_f32_16x16x32_bf16(
              a[rf][ks], bB[1][cf][ks], acc[4 + rf][2 + cf], 0, 0, 0);
    __builtin_amdgcn_s_setprio(0);
    __builtin_amdgcn_s_barrier();
    __builtin_amdgcn_sched_barrier(0);

    // ---- phase 4: quad(1,0) — register-only ----
    asm volatile("s_waitcnt vmcnt(2)" ::: "memory");
    __builtin_amdgcn_s_barrier();
    __builtin_amdgcn_s_setprio(1);
#pragma unroll
    for (int rf = 0; rf < 4; rf++)
#pragma unroll
      for (int cf = 0; cf < 2; cf++)
#pragma unroll
        for (int ks = 0; ks < 2; ks++)
          acc[4 + rf][cf] = __builtin_amdgcn_mfma_f32_16x16x32_bf16(
              a[rf][ks], bB[0][cf][ks], acc[4 + rf][cf], 0, 0, 0);
    __builtin_amdgcn_s_setprio(0);
    __builtin_amdgcn_s_barrier();
    __builtin_amdgcn_sched_barrier(0);
  }

  // epilogue: bias + mask/exp, fused zrow, transpose via swizzled LDS, store.
  // All ds_reads drained (per-phase lgkmcnt) and all waves past the final
  // barrier => smem reusable as tT[256 feat][256 tok] (chunk-XOR swizzled).
  u16* tT = (u16*)smem;
  float fsum[4] = {0.f, 0.f, 0.f, 0.f};
#pragma unroll
  for (int rf = 0; rf < 8; rf++)
#pragma unroll
    for (int r = 0; r < 4; r++) {
      const int tok = wm * 128 + rf * 16 + (lane >> 4) * 4 + r;
      const float mv = mask[m0 + tok];
#pragma unroll
      for (int cf = 0; cf < 4; cf++) {
        const int feat = wn * 64 + cf * 16 + (lane & 15);
        const float aV = acc[rf][cf][r] + bias[n0 + feat];
        float o;
        if (z)
          o = aV * mv;
        else
          o = (mv > 0.5f) ? __expf(fminf(aV, 30.0f)) : 0.0f;
        const u16 ob = f2b(o);
        tT[feat * 256 + ((((tok >> 3) ^ (feat & 7)) << 3) | (tok & 7))] = ob;
        if (!z) fsum[cf] += b2f(ob);  // sum rounded values == zrow semantics
      }
    }
  if (!z) {
#pragma unroll
    for (int cf = 0; cf < 4; cf++) {
      float s = fsum[cf];
      s += __shfl_xor(s, 16);
      s += __shfl_xor(s, 32);
      if (lane < 16)
        atomicAdd(&g_Z[b * 1024 + n0 + wn * 64 + cf * 16 + lane], s);
    }
  }
  __syncthreads();
  const size_t gbase = (size_t)b * (1024 * 4096) + (size_t)n0 * 4096 + t0;
#pragma unroll
  for (int u = 0; u < 16; u++) {
    const int id = u * 512 + tid;
    const int feat = id >> 5, c = id & 31;
    uint4 val = *(const uint4*)&tT[feat * 256 + ((c ^ (feat & 7)) << 3)];
    *(uint4*)(outT + gbase + (size_t)feat * 4096 + c * 8) = val;
  }
}

// ------------------------------------------------------------- att GEMM
// attp[kc][bh][d][l] = sum_{t in 256-chunk kc} ekT[b][h*128+d][t]*vvT[b][h*128+l][t]
__global__ __launch_bounds__(256) void gemm_att() {
  __shared__ __align__(16) char smem[32768];
  char* A0 = smem;
  char* B0 = smem + 8192;
  char* A1 = smem + 16384;
  char* B1 = smem + 24576;
  const int tid = threadIdx.x, wave = tid >> 6, lane = tid & 63;
  const int kc = blockIdx.x;  // 0..15
  const int bh = blockIdx.y;  // 0..31
  const int b = bh >> 3, h = bh & 7;
  const size_t base = (size_t)b * (1024 * 4096) + (size_t)(h * 128) * 4096;
  const int wm = wave & 1, wn = wave >> 1;
  const u16* Ag = g_ekT + base + kc * 256;
  const u16* Bg = g_vvT + base + kc * 256;

  f32x4 zero = {0.f, 0.f, 0.f, 0.f};
  f32x4 acc[4][4];
#pragma unroll
  for (int i = 0; i < 4; i++)
#pragma unroll
    for (int j = 0; j < 4; j++) acc[i][j] = zero;

  stage128x32(Ag, 4096, A0, wave, lane);
  stage128x32(Bg, 4096, B0, wave, lane);
  __syncthreads();
  for (int kt = 0; kt < 256; kt += 64) {
    stage128x32(Ag + kt + 32, 4096, A1, wave, lane);
    stage128x32(Bg + kt + 32, 4096, B1, wave, lane);
    tile_mfma(A0, B0, acc, wm, wn, lane);
    __syncthreads();
    if (kt + 64 < 256) {
      stage128x32(Ag + kt + 64, 4096, A0, wave, lane);
      stage128x32(Bg + kt + 64, 4096, B0, wave, lane);
    }
    tile_mfma(A1, B1, acc, wm, wn, lane);
    __syncthreads();
  }

  float* op = g_attp + ((size_t)(kc * 32 + bh)) * 16384;
#pragma unroll
  for (int i = 0; i < 4; i++)
#pragma unroll
    for (int r = 0; r < 4; r++) {
      const int row = wm * 64 + i * 16 + (lane >> 4) * 4 + r;
#pragma unroll
      for (int j = 0; j < 4; j++) {
        const int col = wn * 64 + j * 16 + (lane & 15);
        op[row * 128 + col] = acc[i][j][r];
      }
    }
}

// ------------------------------------- reduce partials, /Z, store attT[bh][l][d]
__global__ __launch_bounds__(256) void attnorm_kernel() {
  const int bh = blockIdx.x;
  const int b = bh >> 3, h = bh & 7;
  const int tid = threadIdx.x;
  __shared__ float Zl[128];
  if (tid < 128) Zl[tid] = fmaxf(g_Z[b * 1024 + h * 128 + tid], 1e-30f);
  __syncthreads();
  const int i0 = blockIdx.y * 2048;
  for (int i = i0 + tid; i < i0 + 2048; i += 256) {
    const int d = i >> 7, l = i & 127;
    float s = 0.f;
#pragma unroll
    for (int c = 0; c < 16; c++) s += g_attp[((size_t)(c * 32 + bh)) * 16384 + i];
    g_attT[(size_t)bh * 16384 + l * 128 + d] = f2b(s / Zl[d]);
  }
}

// ---------------------------------------------------------- fused q + y
// 1-D grid 1024, XCD swizzle: c=L&7, k=L>>3; m0 = c+8*(k>>3); h = k&7.
__global__ __launch_bounds__(256) void gemm_qy(const float* __restrict__ bq,
                                               const float* __restrict__ x,
                                               float* __restrict__ out) {
  __shared__ __align__(16) char smem[51200];
  __shared__ float zqp[2][128];
  char* A0 = smem;
  char* B0 = smem + 8192;
  char* A1 = smem + 16384;
  char* B1 = smem + 24576;
  u16* qs = (u16*)smem;            // [token][feature] 128x136 padded (34816B)
  char* C0 = smem + 34816;         // phase-2 attT tile dbuf
  char* C1 = smem + 43008;
  const int tid = threadIdx.x, wave = tid >> 6, lane = tid & 63;
  const int L = blockIdx.x;
  const int c = L & 7;
  const int k = L >> 3;              // 0..127
  const int h = k & 7;               // head
  const int m0 = (c + 8 * (k >> 3)) * 128;  // token block, m0%8 == XCD
  const int b = m0 >> 12;
  const int bh = b * 8 + h;
  const int wm = wave & 1, wn = wave >> 1;
  const u16* Ag = g_xn + (size_t)m0 * 1024;
  const u16* Bg = g_WT[0] + (size_t)(h * 128) * 1024;
  const u16* Cg = g_attT + (size_t)bh * 16384;

  f32x4 zero = {0.f, 0.f, 0.f, 0.f};
  f32x4 acc[4][4];
#pragma unroll
  for (int i = 0; i < 4; i++)
#pragma unroll
    for (int j = 0; j < 4; j++) acc[i][j] = zero;

  // phase 1: q = xn @ WqT[head rows], 2-phase pipelined
  stage128x32(Ag, 1024, A0, wave, lane);
  stage128x32(Bg, 1024, B0, wave, lane);
  __syncthreads();
  for (int k0 = 0; k0 < 1024; k0 += 64) {
    stage128x32(Ag + k0 + 32, 1024, A1, wave, lane);
    stage128x32(Bg + k0 + 32, 1024, B1, wave, lane);
    tile_mfma(A0, B0, acc, wm, wn, lane);
    __syncthreads();
    if (k0 + 64 < 1024) {
      stage128x32(Ag + k0 + 64, 1024, A0, wave, lane);
      stage128x32(Bg + k0 + 64, 1024, B0, wave, lane);
    }
    tile_mfma(A1, B1, acc, wm, wn, lane);
    __syncthreads();
  }

  // prefetch phase-2 B tile 0 now; latency hides under epilogue-1 VALU work
  stage128x32(Cg, 128, C0, wave, lane);

  // epilogue 1: exp (clamped), store to qs, row-sums
#pragma unroll
  for (int i = 0; i < 4; i++)
#pragma unroll
    for (int r = 0; r < 4; r++) {
      const int rowl = wm * 64 + i * 16 + (lane >> 4) * 4 + r;
      float rs = 0.f;
#pragma unroll
      for (int j = 0; j < 4; j++) {
        const int coll = wn * 64 + j * 16 + (lane & 15);
        const float e = __expf(fminf(acc[i][j][r] + bq[h * 128 + coll], 30.0f));
        qs[rowl * 136 + coll] = f2b(e);
        rs += e;
      }
      rs += __shfl_xor(rs, 1);
      rs += __shfl_xor(rs, 2);
      rs += __shfl_xor(rs, 4);
      rs += __shfl_xor(rs, 8);
      if ((lane & 15) == 0) zqp[wn][rowl] = rs;
    }
  __syncthreads();  // qs visible; C0 prefetch drained

  // phase 2: y = qs @ attT[bh]^T  (K = 128), B double-buffered
  f32x4 acc2[4][4];
#pragma unroll
  for (int i = 0; i < 4; i++)
#pragma unroll
    for (int j = 0; j < 4; j++) acc2[i][j] = zero;

  for (int k0 = 0; k0 < 128; k0 += 64) {
    stage128x32(Cg + k0 + 32, 128, C1, wave, lane);
    {
      bf16x8 af[4], bfr[4];
#pragma unroll
      for (int i = 0; i < 4; i++)
        af[i] = *(const bf16x8*)&qs[(wm * 64 + i * 16 + (lane & 15)) * 136 + k0 + (lane >> 4) * 8];
#pragma unroll
      for (int j = 0; j < 4; j++) bfr[j] = frag_ld(C0, wn * 64 + j * 16 + (lane & 15), lane);
#pragma unroll
      for (int i = 0; i < 4; i++)
#pragma unroll
        for (int j = 0; j < 4; j++)
          acc2[i][j] = __builtin_amdgcn_mfma_f32_16x16x32_bf16(af[i], bfr[j], acc2[i][j], 0, 0, 0);
    }
    __syncthreads();
    if (k0 + 64 < 128) stage128x32(Cg + k0 + 64, 128, C0, wave, lane);
    {
      bf16x8 af[4], bfr[4];
#pragma unroll
      for (int i = 0; i < 4; i++)
        af[i] = *(const bf16x8*)&qs[(wm * 64 + i * 16 + (lane & 15)) * 136 + k0 + 32 + (lane >> 4) * 8];
#pragma unroll
      for (int j = 0; j < 4; j++) bfr[j] = frag_ld(C1, wn * 64 + j * 16 + (lane & 15), lane);
#pragma unroll
      for (int i = 0; i < 4; i++)
#pragma unroll
        for (int j = 0; j < 4; j++)
          acc2[i][j] = __builtin_amdgcn_mfma_f32_16x16x32_bf16(af[i], bfr[j], acc2[i][j], 0, 0, 0);
    }
    __syncthreads();
  }

  // epilogue 2: out = x + y / Zq  (fp32)
#pragma unroll
  for (int i = 0; i < 4; i++)
#pragma unroll
    for (int r = 0; r < 4; r++) {
      const int rowl = wm * 64 + i * 16 + (lane >> 4) * 4 + r;
      const float zq = fmaxf(zqp[0][rowl] + zqp[1][rowl], 1e-30f);
      const size_t n = (size_t)m0 + rowl;
#pragma unroll
      for (int j = 0; j < 4; j++) {
        const int coll = wn * 64 + j * 16 + (lane & 15);
        const size_t idx = n * 1024 + h * 128 + coll;
        out[idx] = x[idx] + acc2[i][j][r] / zq;
      }
    }
}

// ----------------------------------------------------------------- launch
extern "C" void kernel_launch(void* const* d_in, const int* in_sizes, int n_in,
                              void* d_out, int out_size, void* d_ws, size_t ws_size,
                              hipStream_t stream) {
  const float* x = (const float*)d_in[0];
  const float* mask = (const float*)d_in[1];
  const float* Wq = (const float*)d_in[2];
  const float* bq = (const float*)d_in[3];
  const float* Wk = (const float*)d_in[4];
  const float* bk = (const float*)d_in[5];
  const float* Wv = (const float*)d_in[6];
  const float* bv = (const float*)d_in[7];
  const float* gamma = (const float*)d_in[8];
  const float* beta = (const float*)d_in[9];
  float* out = (float*)d_out;
  (void)d_ws; (void)ws_size;

  prep_kernel<<<dim3(16384 + 3072), 256, 0, stream>>>(x, gamma, beta, Wq, Wk, Wv);
  gemm_kv<<<dim3(512), 512, 0, stream>>>(bk, bv, mask);
  gemm_att<<<dim3(16, 32), 256, 0, stream>>>();
  attnorm_kernel<<<dim3(32, 8), 256, 0, stream>>>();
  gemm_qy<<<dim3(1024), 256, 0, stream>>>(bq, x, out);
}